// Round 4
// baseline (11.011 us; speedup 1.0000x reference)
//
#include <hip/hip_runtime.h>
#include <hip/hip_bf16.h>

// Reference collapse (T=1 decode):
//   tril(ones(1,S)) keeps only s=0; length >= 1 always, so softmax == 1.0 at s=0.
//   attn[b,0,h,:] = bf16(cache_v_after_update[b, pos0, h, :]),
//   pos0 = (kv_idx+1 - min(kv_idx+1, C)) % C; updated slot u = kv_idx % C.
//   pos0 == u only when kv_idx == 0 (then row = bf16(x@wv + bv)).
//   y[b] = f32(bf16(v_sel[b])) @ wo + bo.  q/k/QK^T/softmax are dead code.
//
// Single dispatch: 256 blocks = 16 batches x 16 f-tiles(64 wide), 1024 thr.
// Common path has ONE barrier: threads read their own 128B kv-row segment
// directly (broadcast within 32-thread group), FMA vs pre-issued wo panel,
// wave shfl_xor pre-reduce, 16-deep LDS partial reduce, plain store.

constexpr int BATCH = 16;
constexpr int FDIM  = 1024;   // F
constexpr int HD    = 1024;   // H*D
constexpr int CLEN  = 4096;   // C

__global__ __launch_bounds__(1024) void mha_decode_fused(
    const float* __restrict__ x,        // [B,1,F]
    const int*   __restrict__ kv_idx,   // [B]
    const float* __restrict__ kv_value, // [B,C,HD]
    const float* __restrict__ wv,       // [F,HD]
    const float* __restrict__ bv,       // [HD]
    const float* __restrict__ wo,       // [HD,F]
    const float* __restrict__ bo,       // [F]
    float*       __restrict__ y)        // [B,F]
{
    const int bid = blockIdx.x;
    const int ft  = bid & 15;          // f-tile; bid%8==ft%8 -> XCD locality
    const int b   = bid >> 4;          // batch
    const int t   = threadIdx.x;       // 0..1023
    const int fl2 = t & 31;            // f-pair within tile
    const int jq  = t >> 5;            // j-quadrant 0..31 (32 j each)
    const int f0  = ft * 64 + fl2 * 2;

    __shared__ float part[16 * 64];    // per-wave partials
    __shared__ float xs[FDIM];         // rare-path staging
    __shared__ float vsels[HD];        // rare-path vsel

    // ---- Issue wo panel loads first (independent of everything else).
    const float* wop = wo + (size_t)(jq * 32) * FDIM + f0;
    float2 w[32];
#pragma unroll
    for (int i = 0; i < 32; ++i)
        w[i] = *reinterpret_cast<const float2*>(wop + (size_t)i * FDIM);

    const int idx     = kv_idx[b];     // block-uniform -> scalar load
    const int new_idx = idx + 1;
    const int length  = new_idx < CLEN ? new_idx : CLEN;
    const int pos0    = (new_idx - length) % CLEN;  // non-negative
    const int upd     = idx % CLEN;

    float a0 = 0.f, a1 = 0.f;
    if (pos0 != upd) {
        // Common path: direct 128B segment of the selected kv row; no LDS.
        const float4* src = reinterpret_cast<const float4*>(
            kv_value + ((size_t)b * CLEN + (size_t)pos0) * HD + jq * 32);
#pragma unroll
        for (int i = 0; i < 8; ++i) {
            const float4 q = src[i];
            const float v0 = __bfloat162float(__float2bfloat16(q.x));
            const float v1 = __bfloat162float(__float2bfloat16(q.y));
            const float v2 = __bfloat162float(__float2bfloat16(q.z));
            const float v3 = __bfloat162float(__float2bfloat16(q.w));
            a0 = fmaf(v0, w[4*i+0].x, a0); a1 = fmaf(v0, w[4*i+0].y, a1);
            a0 = fmaf(v1, w[4*i+1].x, a0); a1 = fmaf(v1, w[4*i+1].y, a1);
            a0 = fmaf(v2, w[4*i+2].x, a0); a1 = fmaf(v2, w[4*i+2].y, a1);
            a0 = fmaf(v3, w[4*i+3].x, a0); a1 = fmaf(v3, w[4*i+3].y, a1);
        }
    } else {
        // Rare path (kv_idx == 0): fresh v projection row via LDS.
        xs[t] = x[b * FDIM + t];
        __syncthreads();
        float a = bv[t];
        for (int f = 0; f < FDIM; ++f)
            a = fmaf(xs[f], wv[(size_t)f * HD + t], a);
        vsels[t] = __bfloat162float(__float2bfloat16(a));
        __syncthreads();
#pragma unroll
        for (int i = 0; i < 32; ++i) {
            const float v = vsels[jq * 32 + i];
            a0 = fmaf(v, w[i].x, a0);
            a1 = fmaf(v, w[i].y, a1);
        }
    }

    // ---- Wave pre-reduce: lanes l and l^32 share fl2, adjacent jq.
    a0 += __shfl_xor(a0, 32);
    a1 += __shfl_xor(a1, 32);

    const int lane = t & 63;
    const int wid  = t >> 6;           // wave 0..15
    if (lane < 32) {
        part[wid * 64 + lane * 2]     = a0;
        part[wid * 64 + lane * 2 + 1] = a1;
    }
    __syncthreads();

    // ---- Final reduce: 16 partials per f-column (conflict-free), store.
    if (t < 64) {
        float acc = bo[ft * 64 + t];
#pragma unroll
        for (int j = 0; j < 16; ++j)
            acc += part[j * 64 + t];
        y[b * FDIM + ft * 64 + t] = acc;
    }
}

extern "C" void kernel_launch(void* const* d_in, const int* in_sizes, int n_in,
                              void* d_out, int out_size, void* d_ws, size_t ws_size,
                              hipStream_t stream) {
    // setup_inputs order:
    // 0:x 1:mask 2:kv_idx 3:kv_key 4:kv_value 5:wq 6:bq 7:wk 8:bk 9:wv 10:bv 11:wo 12:bo
    const float* x        = (const float*)d_in[0];
    const int*   kv_idx   = (const int*)  d_in[2];
    const float* kv_value = (const float*)d_in[4];
    const float* wv       = (const float*)d_in[9];
    const float* bv       = (const float*)d_in[10];
    const float* wo       = (const float*)d_in[11];
    const float* bo       = (const float*)d_in[12];
    float*       y        = (float*)d_out;

    mha_decode_fused<<<dim3(BATCH * 16), 1024, 0, stream>>>(
        x, kv_idx, kv_value, wv, bv, wo, bo, y);
}